// Round 1
// baseline (206.710 us; speedup 1.0000x reference)
//
#include <hip/hip_runtime.h>
#include <math.h>

#define D 64
#define K 512
#define ROWS 131072       // 32*64*64
#define NELEM (ROWS * D)  // 8388608
#define TGAP 64.0f        // flag threshold in 2^20-scaled units (= 6.1e-5 unscaled)
#define FLAGBIT (1 << 30)
#define RPB 128           // rows per block: 4 waves x 32 rows
#define NBLK (ROWS / RPB) // 1024 blocks -> 4 blocks/CU

typedef _Float16 half8 __attribute__((ext_vector_type(8)));
typedef float floatx4 __attribute__((ext_vector_type(4)));

// ws layout (bytes):
//   [0,8)            double loss accumulator
//   [8,12)           uint32 ticket counter (fused finalize)
//   [4096,6144)      float  Bn20[512]    column norms * 2^20 (numpy order, exact scale)
//   [8192,73728)     _Float16 gH[32768]  hi B-fragments, MFMA fragment order
//   [73728,139264)   _Float16 gL[32768]  lo B-fragments

// ---------------------------------------------------------------------------
// Setup: codebook -> scaled fp16 hi/lo in B-fragment order (global), + norms,
// + zero the loss/ticket words (replaces the hipMemsetAsync launch).
// frag layout: half index = (((n>>4)*2 + (k>>5))*64 + ((k>>3)&3)*16 + (n&15))*8 + (k&7)
// ---------------------------------------------------------------------------
__global__ __launch_bounds__(512) void vq_setup(const float* __restrict__ cb,
                                                _Float16* __restrict__ gH,
                                                _Float16* __restrict__ gL,
                                                float* __restrict__ Bn,
                                                unsigned long long* __restrict__ zws) {
    int idx = blockIdx.x * 512 + threadIdx.x;   // 64 blocks x 512 = 32768
    int k = idx >> 9, n = idx & 511;
    float c = cb[idx];
    float t = c * 4096.0f;                      // 2^12, exact
    _Float16 ch = (_Float16)t;
    float r = t - (float)ch;                    // exact
    _Float16 cl = (_Float16)(r * 4096.0f);      // scale 2^24
    int off = (((n >> 4) * 2 + (k >> 5)) * 64 + ((k >> 3) & 3) * 16 + (n & 15)) * 8 + (k & 7);
    gH[off] = ch;
    gL[off] = cl;
    if (blockIdx.x == 1 && threadIdx.x < 4) zws[threadIdx.x] = 0ull;  // loss + ticket
    if (blockIdx.x == 0) {
#pragma clang fp contract(off)
        int j = threadIdx.x;
        float b = 0.f;
        for (int kk = 0; kk < D; ++kk) { float cc = cb[kk * K + j]; b = b + cc * cc; }
        Bn[j] = b * 0x1p20f;                    // exact power-of-2 scale
    }
}

// ---------------------------------------------------------------------------
// Main: MFMA filter, 256 thr = 4 waves, 32 rows/wave (2 tiles of 16).
// A pre-scaled by -2 so MFMA accumulates (B - 2M)*2^20 directly (C-init = Bj).
// Fused exact rescan of flagged rows (block-local bitmap) + ticket finalize.
// ---------------------------------------------------------------------------
__global__ __launch_bounds__(256, 4) void vq_main(const float* __restrict__ x,
                                                  const float* __restrict__ cb,
                                                  const _Float16* __restrict__ gH,
                                                  const _Float16* __restrict__ gL,
                                                  const float* __restrict__ Bn,
                                                  float* __restrict__ out,
                                                  double* __restrict__ loss_acc,
                                                  unsigned int* __restrict__ ticket) {
    __shared__ float ldsB[K];
    __shared__ int rowinfo[4][32];
    __shared__ unsigned int flagbits[4];
    __shared__ float wavesum[4];

    const int tid = threadIdx.x;
    const int lane = tid & 63;
    const int w = tid >> 6;
    const int quad = lane >> 4;
    const int nn = lane & 15;

    ldsB[tid] = Bn[tid];
    ldsB[tid + 256] = Bn[tid + 256];
    if (tid < 4) flagbits[tid] = 0;

    const int rowBase = blockIdx.x * RPB + w * 32;

    // A-fragments: lane holds A[m=nn][k=quad*8+j] per k-half s, scaled by -2:
    // hi at -2^9*x, residual *4096 -> lo pairs with bl at combined 2^-12 shift.
    half8 xh[2][2], xl[2][2];
    #pragma unroll
    for (int tt = 0; tt < 2; ++tt) {
        #pragma unroll
        for (int s = 0; s < 2; ++s) {
            const float* xp = x + (size_t)(rowBase + tt * 16 + nn) * D + s * 32 + quad * 8;
            float4 v0 = *(const float4*)xp;
            float4 v1 = *(const float4*)(xp + 4);
            float vv[8] = {v0.x, v0.y, v0.z, v0.w, v1.x, v1.y, v1.z, v1.w};
            #pragma unroll
            for (int j = 0; j < 8; ++j) {
                float t = vv[j] * -512.0f;       // -2^9, exact
                _Float16 h = (_Float16)t;
                float r = t - (float)h;          // exact
                xh[tt][s][j] = h;
                xl[tt][s][j] = (_Float16)(r * 4096.0f);  // scale -2*2^20
            }
        }
    }
    __syncthreads();

    float m1[2][4], m2[2][4];
    int   i1[2][4];
    #pragma unroll
    for (int tt = 0; tt < 2; ++tt)
        #pragma unroll
        for (int r = 0; r < 4; ++r) { m1[tt][r] = INFINITY; m2[tt][r] = INFINITY; i1[tt][r] = 0; }

    const half8* bHp = (const half8*)gH;
    const half8* bLp = (const half8*)gL;

    #pragma unroll 2
    for (int t = 0; t < 32; ++t) {
        half8 bh0 = bHp[(t * 2 + 0) * 64 + lane];   // coalesced 16B/lane, L2-resident
        half8 bl0 = bLp[(t * 2 + 0) * 64 + lane];
        half8 bh1 = bHp[(t * 2 + 1) * 64 + lane];
        half8 bl1 = bLp[(t * 2 + 1) * 64 + lane];
        int col = t * 16 + nn;
        float Bj = ldsB[col];                       // B*2^20
        #pragma unroll
        for (int tt = 0; tt < 2; ++tt) {
            floatx4 a1 = {Bj, Bj, Bj, Bj};          // C-init: accumulate (B - 2M_hi)*2^20
            floatx4 a2 = {0.f, 0.f, 0.f, 0.f};     // cross terms at -2*2^32
            a2 = __builtin_amdgcn_mfma_f32_16x16x32_f16(xl[tt][0], bh0, a2, 0, 0, 0);
            a2 = __builtin_amdgcn_mfma_f32_16x16x32_f16(xh[tt][0], bl0, a2, 0, 0, 0);
            a1 = __builtin_amdgcn_mfma_f32_16x16x32_f16(xh[tt][0], bh0, a1, 0, 0, 0);
            a2 = __builtin_amdgcn_mfma_f32_16x16x32_f16(xl[tt][1], bh1, a2, 0, 0, 0);
            a2 = __builtin_amdgcn_mfma_f32_16x16x32_f16(xh[tt][1], bl1, a2, 0, 0, 0);
            a1 = __builtin_amdgcn_mfma_f32_16x16x32_f16(xh[tt][1], bh1, a1, 0, 0, 0);
            #pragma unroll
            for (int r = 0; r < 4; ++r) {
                float g = fmaf(0x1p-12f, a2[r], a1[r]);      // (B - 2M) * 2^20
                float old1 = m1[tt][r];
                bool c1 = g < old1;
                m2[tt][r] = fminf(fmaxf(g, old1), m2[tt][r]);
                m1[tt][r] = c1 ? g : old1;
                i1[tt][r] = c1 ? col : i1[tt][r];            // strict <, j ascending
            }
        }
    }

    // merge best-2 across the 16 col-lanes (butterfly over low 4 lane bits)
    #pragma unroll
    for (int dlt = 1; dlt < 16; dlt <<= 1) {
        #pragma unroll
        for (int tt = 0; tt < 2; ++tt)
            #pragma unroll
            for (int r = 0; r < 4; ++r) {
                float om1 = __shfl_xor(m1[tt][r], dlt);
                int   oi1 = __shfl_xor(i1[tt][r], dlt);
                float om2 = __shfl_xor(m2[tt][r], dlt);
                bool ofirst = (om1 < m1[tt][r]) || (om1 == m1[tt][r] && oi1 < i1[tt][r]);
                float l1   = ofirst ? m1[tt][r] : om1;
                float cand = ofirst ? om2 : m2[tt][r];
                m1[tt][r] = ofirst ? om1 : m1[tt][r];
                i1[tt][r] = ofirst ? oi1 : i1[tt][r];
                m2[tt][r] = fminf(cand, l1);
            }
    }

    // record results; flagged rows -> per-wave LDS bitmap word
    if (nn == 0) {
        #pragma unroll
        for (int tt = 0; tt < 2; ++tt)
            #pragma unroll
            for (int r = 0; r < 4; ++r) {
                int rl = tt * 16 + quad * 4 + r;
                bool flg = (m2[tt][r] - m1[tt][r]) < TGAP;
                rowinfo[w][rl] = i1[tt][r] | (flg ? FLAGBIT : 0);
                if (flg) atomicOr(&flagbits[w], 1u << rl);
            }
    }
    __syncthreads();

    // coalesced output + loss for certain rows
    float lsum = 0.f;
    #pragma unroll
    for (int tt = 0; tt < 2; ++tt) {
        #pragma unroll
        for (int p = 0; p < 4; ++p) {
            int rl = tt * 16 + p * 4 + quad;
            int info = rowinfo[w][rl];
            if (!(info & FLAGBIT)) {
                int j = info & 511;
                int kb = nn * 4;
                float q0 = cb[(kb + 0) * K + j];
                float q1 = cb[(kb + 1) * K + j];
                float q2 = cb[(kb + 2) * K + j];
                float q3 = cb[(kb + 3) * K + j];
                size_t row = (size_t)rowBase + rl;
                float4 xv = *(const float4*)(x + row * D + kb);
                float e0 = q0 - xv.x, e1 = q1 - xv.y, e2 = q2 - xv.z, e3 = q3 - xv.w;
                lsum += e0 * e0 + e1 * e1 + e2 * e2 + e3 * e3;
                *(float4*)(out + row * D + kb) = make_float4(q0, q1, q2, q3);
            }
        }
    }

    // fused exact rescan: this wave handles its own 32-row bitmap word.
    // Exact numpy-order pipeline; lane handles 8 columns (j = lane + 64m).
    unsigned int fmask = flagbits[w];
    if (fmask) {
#pragma clang fp contract(off)
        float bn[8];
        #pragma unroll
        for (int m = 0; m < 8; ++m) bn[m] = 0.f;
        for (int k = 0; k < D; ++k) {
            const float* crow = cb + k * K + lane;
            #pragma unroll
            for (int m = 0; m < 8; ++m) {
                float c = crow[m * 64];
                bn[m] = bn[m] + c * c;
            }
        }
        while (fmask) {
            int b = __builtin_ctz(fmask);
            fmask &= fmask - 1;
            int row = rowBase + b;
            const float* xr = x + (size_t)row * D;
            // A = np.sum(x**2, axis=1): pairwise n=64 emulation
            float A0;
            {
                float rr[8];
                #pragma unroll
                for (int l = 0; l < 8; ++l) rr[l] = xr[l] * xr[l];
                #pragma unroll
                for (int m = 1; m < 8; ++m)
                    #pragma unroll
                    for (int l = 0; l < 8; ++l) {
                        float q = xr[8 * m + l] * xr[8 * m + l];
                        rr[l] = rr[l] + q;
                    }
                A0 = ((rr[0] + rr[1]) + (rr[2] + rr[3])) + ((rr[4] + rr[5]) + (rr[6] + rr[7]));
            }
            float a[8];
            #pragma unroll
            for (int m = 0; m < 8; ++m) a[m] = 0.f;
            for (int k = 0; k < D; ++k) {
                float xk = xr[k];
                const float* crow = cb + k * K + lane;
                #pragma unroll
                for (int m = 0; m < 8; ++m)
                    a[m] = fmaf(xk, crow[m * 64], a[m]);   // sequential-k fma chain
            }
            float db = INFINITY; int jb = 0x7fffffff;
            #pragma unroll
            for (int m = 0; m < 8; ++m) {
                float s = A0 + bn[m];
                float t2 = 2.0f * a[m];
                float d = s - t2;                  // fl(fl(A+B) - fl(2M))
                int j = lane + (m << 6);
                if (d < db) { db = d; jb = j; }
            }
            for (int s = 1; s < 64; s <<= 1) {     // first-index global argmin
                float od = __shfl_xor(db, s);
                int oj = __shfl_xor(jb, s);
                if ((od < db) || (od == db && oj < jb)) { db = od; jb = oj; }
            }
            float q = cb[lane * K + jb];
            out[(size_t)row * D + lane] = q;
            float e = q - xr[lane];
            lsum += e * e;
        }
    }

    #pragma unroll
    for (int off = 32; off > 0; off >>= 1) lsum += __shfl_down(lsum, off);
    if (lane == 0) wavesum[w] = lsum;
    __syncthreads();
    if (tid == 0) {
        double tot = (double)wavesum[0] + (double)wavesum[1]
                   + (double)wavesum[2] + (double)wavesum[3];
        atomicAdd(loss_acc, tot);
        __threadfence();
        unsigned int my = atomicAdd(ticket, 1u);
        if (my == (unsigned int)(gridDim.x - 1)) {
            // last block: all prior loss adds are ordered before their tickets
            double total = atomicAdd(loss_acc, 0.0);
            out[NELEM] = (float)(total * (1.25 / (double)NELEM));  // (1+beta)*mean
        }
    }
}

extern "C" void kernel_launch(void* const* d_in, const int* in_sizes, int n_in,
                              void* d_out, int out_size, void* d_ws, size_t ws_size,
                              hipStream_t stream) {
    const float* x  = (const float*)d_in[0];   // [32,64,64,64] fp32
    const float* cb = (const float*)d_in[1];   // [64,512] fp32
    float* out = (float*)d_out;                // [8388608] out + [1] loss
    double* loss_acc     = (double*)d_ws;
    unsigned int* ticket = (unsigned int*)((char*)d_ws + 8);
    float* Bn        = (float*)((char*)d_ws + 4096);
    _Float16* gH     = (_Float16*)((char*)d_ws + 8192);
    _Float16* gL     = (_Float16*)((char*)d_ws + 73728);

    vq_setup<<<64, 512, 0, stream>>>(cb, gH, gL, Bn, (unsigned long long*)d_ws);
    vq_main<<<NBLK, 256, 0, stream>>>(x, cb, gH, gL, Bn, out, loss_acc, ticket);
}